// Round 9
// baseline (1558.719 us; speedup 1.0000x reference)
//
#include <hip/hip_runtime.h>

// EdgeConv block. Round 9: dist kernel re-parallelized for occupancy.
// r8 counters: Occupancy 23% (grid 512 x 4 waves = 2 waves/SIMD, grid-limited),
// MfmaUtil 5.6%, VALUBusy 25% -> ~70% latency stalls. Fix: 8 waves/block (512 thr),
// each wave scans 1/8 of j; 16 waves/CU (4/SIMD). Merge epilogue now 16 lists/row
// (64KB LDS, aliased). Selection logic identical to the r8-validated kernel.

#define N_PTS 16384
#define FDIM  64
#define HDIM  128
#define KNN   16
#define NEDGE (N_PTS * KNN)

#define SENT_KEY 0xFF800000FFFFFFFFull
#define MAXU64   0xFFFFFFFFFFFFFFFFull
#define EPS_MARGIN 1.0f

typedef __attribute__((ext_vector_type(8)))  short bf16x8;
typedef __attribute__((ext_vector_type(16))) float f32x16;

// ---------------------------------------------------------------- norms
__global__ __launch_bounds__(256)
void k_norms(const float* __restrict__ X, float* __restrict__ n2) {
  const int r = blockIdx.x * 256 + threadIdx.x;
  const float4* x4 = reinterpret_cast<const float4*>(X) + (size_t)r * (FDIM / 4);
  float p[16];
#pragma unroll
  for (int i = 0; i < 16; ++i) {
    const float4 v = x4[i];
    p[i] = (v.x * v.x + v.y * v.y) + (v.z * v.z + v.w * v.w);
  }
#pragma unroll
  for (int s = 1; s < 16; s <<= 1) {
#pragma unroll
    for (int i = 0; i < 16; i += 2 * s) p[i] += p[i + s];
  }
  n2[r] = p[0];
}

// ---------------------------------------------------------------- bf16 hi/lo split of X
__global__ __launch_bounds__(256)
void k_split(const float* __restrict__ X, unsigned short* __restrict__ Xh,
             unsigned short* __restrict__ Xl) {
  const int t = blockIdx.x * 256 + threadIdx.x;           // 8 elems per thread
  const float4* X4 = reinterpret_cast<const float4*>(X);
  const float4 v0 = X4[(size_t)t * 2];
  const float4 v1 = X4[(size_t)t * 2 + 1];
  const float xs[8] = {v0.x, v0.y, v0.z, v0.w, v1.x, v1.y, v1.z, v1.w};
  unsigned int h[8], l[8];
#pragma unroll
  for (int e = 0; e < 8; ++e) {
    const unsigned int u = __float_as_uint(xs[e]);
    h[e] = (u + 0x7FFFu + ((u >> 16) & 1u)) >> 16;        // bf16 RNE
    const float hf = __uint_as_float(h[e] << 16);
    const float r = xs[e] - hf;                            // exact (Sterbenz)
    const unsigned int v = __float_as_uint(r);
    l[e] = (v + 0x7FFFu + ((v >> 16) & 1u)) >> 16;
  }
  uint4 hw, lw;
  hw.x = h[0] | (h[1] << 16); hw.y = h[2] | (h[3] << 16);
  hw.z = h[4] | (h[5] << 16); hw.w = h[6] | (h[7] << 16);
  lw.x = l[0] | (l[1] << 16); lw.y = l[2] | (l[3] << 16);
  lw.z = l[4] | (l[5] << 16); lw.w = l[6] | (l[7] << 16);
  reinterpret_cast<uint4*>(Xh)[t] = hw;
  reinterpret_cast<uint4*>(Xl)[t] = lw;
}

// ---------------------------------------------------------------- P,Q
__global__ __launch_bounds__(256)
void k_pq(const float* __restrict__ X, const float* __restrict__ W1,
          const float* __restrict__ b1, float* __restrict__ P, float* __restrict__ Q) {
  const int h4 = threadIdx.x & 31;
  const int rsub = threadIdx.x >> 5;
  const int row = blockIdx.x * 8 + rsub;
  const float* x = X + (size_t)row * FDIM;
  const float4* W14 = reinterpret_cast<const float4*>(W1);
  float4 at = make_float4(0.f, 0.f, 0.f, 0.f);
  float4 ab = make_float4(0.f, 0.f, 0.f, 0.f);
#pragma unroll 8
  for (int f = 0; f < FDIM; ++f) {
    const float xv = x[f];
    const float4 wt = W14[(size_t)f * 32 + h4];
    const float4 wb = W14[(size_t)(FDIM + f) * 32 + h4];
    at.x = fmaf(xv, wt.x, at.x); at.y = fmaf(xv, wt.y, at.y);
    at.z = fmaf(xv, wt.z, at.z); at.w = fmaf(xv, wt.w, at.w);
    ab.x = fmaf(xv, wb.x, ab.x); ab.y = fmaf(xv, wb.y, ab.y);
    ab.z = fmaf(xv, wb.z, ab.z); ab.w = fmaf(xv, wb.w, ab.w);
  }
  const float4 bb = reinterpret_cast<const float4*>(b1)[h4];
  float4 pv;
  pv.x = at.x - ab.x + bb.x; pv.y = at.y - ab.y + bb.y;
  pv.z = at.z - ab.z + bb.z; pv.w = at.w - ab.w + bb.w;
  reinterpret_cast<float4*>(P)[(size_t)row * 32 + h4] = pv;
  reinterpret_cast<float4*>(Q)[(size_t)row * 32 + h4] = ab;
}

// ---------------------------------------------------------------- MFMA distance + top-16
// Block: 512 thr = 8 waves; i-tile = 32 rows; wave w scans j-chunks ct (jb=(ct*8+w)*32).
// Per chunk: A = Xj rows (hi/lo), B = Xi^T (persistent), C[j,i] via 3-split bf16 MFMA.
// Lane owns i = i0+(lane&31), 16 j-scores in acc regs. Shared per-i threshold (min of
// 16 owner slots' exact 16th-best) -> approx filter (margin) -> per-thread LDS ring ->
// ballot-gated exact fp32 re-score flush (identical chain + u64 tie keys as r2/r8).
// LDS (64KB): Xi fp32 [32][64] swz @0 (8KB); thr [16][32] @8192 (2KB);
//             ring u32 [6][512] @10240 (12KB); merge mb u64 [32][16][16] aliases all (64KB).
__global__ __launch_bounds__(512, 4)
void k_dist_mfma(const float* __restrict__ X, const unsigned short* __restrict__ Xh,
                 const unsigned short* __restrict__ Xl, const float* __restrict__ n2g,
                 int* __restrict__ knn) {
  __shared__ __align__(16) char smem[65536];
  float* Xi = reinterpret_cast<float*>(smem);                    // [32][64] swizzled
  float* thr = reinterpret_cast<float*>(smem + 8192);            // [16][32]
  unsigned int* ring = reinterpret_cast<unsigned int*>(smem + 10240); // [6][512]

  const int tid = threadIdx.x;
  const int w = tid >> 6, lane = tid & 63;
  const int li = lane & 31, hf = lane >> 5;
  const int i0 = blockIdx.x * 32;
  const int slot = w * 2 + hf;            // 0..15

  const float4* X4 = reinterpret_cast<const float4*>(X);

  thr[tid < 512 ? tid : 0] = __int_as_float(0x7f800000);  // 512 entries, 1:1
  // stage Xi fp32, swizzled for the exact-recompute reads (one float4 per thread)
  {
    const int u = tid;  // 512 = 32 rows x 16 float4s
    const int row = u >> 4, c4 = u & 15;
    const float4 v = X4[(size_t)(i0 + row) * 16 + c4];
    *reinterpret_cast<float4*>(&Xi[row * 64 + ((c4 ^ (row & 15)) * 4)]) = v;
  }

  // persistent B-frags (Xi hi/lo), lane supplies col li, k = s*16 + hf*8 + e
  bf16x8 bh[4], bl[4];
#pragma unroll
  for (int s = 0; s < 4; ++s) {
    const size_t o = (size_t)(i0 + li) * 64 + s * 16 + hf * 8;
    bh[s] = *reinterpret_cast<const bf16x8*>(Xh + o);
    bl[s] = *reinterpret_cast<const bf16x8*>(Xl + o);
  }
  const float n2i = n2g[i0 + li];

  unsigned long long list[16];
#pragma unroll
  for (int p = 0; p < 16; ++p) list[p] = SENT_KEY;
  int cnt = 0;
  float thrm = __int_as_float(0x7f800000);

  __syncthreads();

  auto flush = [&]() {
#pragma unroll 1
    for (int s = 0; s < 6; ++s) {
      if (s < cnt) {
        const unsigned int j = ring[s * 512 + tid];
        float a = 0.0f;
        const float4* xj4 = reinterpret_cast<const float4*>(X + (size_t)j * 64);
#pragma unroll
        for (int c4 = 0; c4 < 16; ++c4) {   // EXACT r2 fmaf chain, f ascending
          const float4 xiv =
              *reinterpret_cast<const float4*>(&Xi[li * 64 + ((c4 ^ (li & 15)) * 4)]);
          const float4 xjv = xj4[c4];
          a = fmaf(xiv.x, xjv.x, a); a = fmaf(xiv.y, xjv.y, a);
          a = fmaf(xiv.z, xjv.z, a); a = fmaf(xiv.w, xjv.w, a);
        }
        const float t = n2i + n2g[j];
        const float sd = __fsub_rn(t, __fmul_rn(2.0f, a));
        unsigned int ub = __float_as_uint(sd);
        ub = (ub & 0x80000000u) ? ~ub : (ub | 0x80000000u);
        const unsigned long long key = ((unsigned long long)ub << 32) | j;
        if (key < list[15]) {
#pragma unroll
          for (int q = 15; q >= 1; --q) {
            const unsigned long long prev = list[q - 1];
            unsigned long long cur = list[q];
            cur = (key < cur) ? key : cur;
            list[q] = (key < prev) ? prev : cur;
          }
          list[0] = (key < list[0]) ? key : list[0];
        }
      }
    }
    cnt = 0;
    const unsigned int ub16 = (unsigned int)(list[15] >> 32);
    const float tf = (ub16 & 0x80000000u) ? __uint_as_float(ub16 & 0x7fffffffu)
                                          : __uint_as_float(~ub16);
    thr[slot * 32 + li] = tf;
    thrm = fminf(thrm, tf);
  };

  for (int ct = 0; ct < 64; ++ct) {
    const int jb = (ct * 8 + w) * 32;
    if ((ct & 3) == 0) {  // refresh shared threshold (stale = larger = safe)
      float m = thr[li];
#pragma unroll
      for (int q = 1; q < 16; ++q) m = fminf(m, thr[q * 32 + li]);
      thrm = m;
    }
    bf16x8 ah[4], al[4];
#pragma unroll
    for (int s = 0; s < 4; ++s) {
      const size_t o = (size_t)(jb + li) * 64 + s * 16 + hf * 8;
      ah[s] = *reinterpret_cast<const bf16x8*>(Xh + o);
      al[s] = *reinterpret_cast<const bf16x8*>(Xl + o);
    }
    float4 nj[4];
#pragma unroll
    for (int q = 0; q < 4; ++q)
      nj[q] = *reinterpret_cast<const float4*>(n2g + jb + q * 8 + hf * 4);

    f32x16 acc0 = {0,0,0,0,0,0,0,0,0,0,0,0,0,0,0,0};
    f32x16 acc1 = {0,0,0,0,0,0,0,0,0,0,0,0,0,0,0,0};
#pragma unroll
    for (int s = 0; s < 4; ++s) {
      acc0 = __builtin_amdgcn_mfma_f32_32x32x16_bf16(ah[s], bh[s], acc0, 0, 0, 0);
      acc1 = __builtin_amdgcn_mfma_f32_32x32x16_bf16(ah[s], bl[s], acc1, 0, 0, 0);
      acc1 = __builtin_amdgcn_mfma_f32_32x32x16_bf16(al[s], bh[s], acc1, 0, 0, 0);
    }

    const float lim = thrm + EPS_MARGIN;
#pragma unroll
    for (int r = 0; r < 16; ++r) {
      const float dot = acc0[r] + acc1[r];
      const float njv = (r & 2) ? ((r & 1) ? nj[r >> 2].w : nj[r >> 2].z)
                                : ((r & 1) ? nj[r >> 2].y : nj[r >> 2].x);
      const float sv = fmaf(-2.0f, dot, n2i + njv);
      if (sv <= lim) {
        ring[cnt * 512 + tid] = (unsigned int)(jb + (r & 3) + 8 * (r >> 2) + 4 * hf);
        ++cnt;
      }
      if ((r & 1) && __any(cnt >= 5)) flush();
    }
  }
  flush();  // drain

  // merge: 16 sorted 16-lists per i -> top 16
  __syncthreads();
  unsigned long long* mb = reinterpret_cast<unsigned long long*>(smem);  // 64KB alias
#pragma unroll
  for (int p = 0; p < 16; ++p) mb[((size_t)li * 16 + slot) * 16 + p] = list[p];
  __syncthreads();
  if (tid < 32) {
    int pp[16];
#pragma unroll
    for (int q = 0; q < 16; ++q) pp[q] = 0;
    for (int pick = 0; pick < KNN; ++pick) {
      unsigned long long best = MAXU64; int bq = 0;
#pragma unroll
      for (int q = 0; q < 16; ++q) {
        const unsigned long long cand =
            (pp[q] < 16) ? mb[((size_t)tid * 16 + q) * 16 + pp[q]] : MAXU64;
        if (cand < best) { best = cand; bq = q; }
      }
      pp[bq]++;
      knn[(size_t)(i0 + tid) * KNN + pick] = (int)(unsigned int)(best & 0xFFFFFFFFULL);
    }
  }
}

// ---------------------------------------------------------------- stats of pre1
__global__ __launch_bounds__(256)
void k_stats_edges(const float* __restrict__ P, const float* __restrict__ Q,
                   const int* __restrict__ idx,
                   double* __restrict__ psum, double* __restrict__ psq) {
  __shared__ double sd[2][128];
  __shared__ double qd[2][128];
  const int t = threadIdx.x;
  const int h = t & 127, half = t >> 7;
  const size_t e0 = (size_t)blockIdx.x * 128;
  double s = 0.0, q = 0.0;
  for (int it = 0; it < 64; ++it) {
    const size_t e = e0 + (size_t)it * 2 + half;
    const int n = (int)(e >> 4);
    const int j = idx[e];
    const float v = P[(size_t)n * HDIM + h] + Q[(size_t)j * HDIM + h];
    s += (double)v;
    q += (double)v * (double)v;
  }
  sd[half][h] = s; qd[half][h] = q;
  __syncthreads();
  if (t < 128) {
    psum[(size_t)blockIdx.x * 128 + t] = sd[0][t] + sd[1][t];
    psq[(size_t)blockIdx.x * 128 + t]  = qd[0][t] + qd[1][t];
  }
}

// ---------------------------------------------------------------- stats reduce -> a,c
__global__ __launch_bounds__(256)
void k_reduce_stats(const double* __restrict__ psum, const double* __restrict__ psq,
                    const float* __restrict__ g, const float* __restrict__ beta,
                    float* __restrict__ aout, float* __restrict__ cout) {
  __shared__ double sbuf[256];
  __shared__ double qbuf[256];
  const int h = blockIdx.x, t = threadIdx.x;
  double s = 0.0, q = 0.0;
  for (int i = t; i < 2048; i += 256) {
    s += psum[(size_t)i * 128 + h];
    q += psq[(size_t)i * 128 + h];
  }
  sbuf[t] = s; qbuf[t] = q;
  __syncthreads();
  for (int st = 128; st > 0; st >>= 1) {
    if (t < st) { sbuf[t] += sbuf[t + st]; qbuf[t] += qbuf[t + st]; }
    __syncthreads();
  }
  if (t == 0) {
    const double cntd = (double)NEDGE;
    const double mu = sbuf[0] / cntd;
    double var = qbuf[0] / cntd - mu * mu;
    if (var < 0.0) var = 0.0;
    const double rs = 1.0 / sqrt(var + 1e-5);
    const double a = (double)g[h] * rs;
    aout[h] = (float)a;
    cout[h] = (float)((double)beta[h] - mu * a);
  }
}

// ---------------------------------------------------------------- GEMM (layers 2 & 3)
template <int MODE>
__global__ __launch_bounds__(256, 2)
void k_gemm(const float* __restrict__ P, const float* __restrict__ Q,
            const int* __restrict__ idx, float* __restrict__ big,
            const float* __restrict__ Wg, const float* __restrict__ bias,
            const float* __restrict__ aff_a, const float* __restrict__ aff_c,
            double* __restrict__ psum, double* __restrict__ psq) {
  __shared__ float A_lds[32][132];
  __shared__ float B_lds[32][132];
  const int tid = threadIdx.x;
  const int tm = tid & 15, tn = tid >> 4;
  const size_t e0 = (size_t)blockIdx.x * 128;

  float acc[2][2][4][4] = {};

  for (int kk = 0; kk < 128; kk += 32) {
    __syncthreads();
    {
      const int k4 = tid & 7;
      const int mrow = tid >> 3;
      const float4 av = reinterpret_cast<const float4*>(aff_a)[(kk >> 2) + k4];
      const float4 cv = reinterpret_cast<const float4*>(aff_c)[(kk >> 2) + k4];
#pragma unroll
      for (int p = 0; p < 4; ++p) {
        const int m = p * 32 + mrow;
        const size_t e = e0 + m;
        float4 hv;
        if (MODE == 2) {
          const int n = (int)(e >> 4);
          const int j = idx[e];
          const float4 pv = reinterpret_cast<const float4*>(P)[(size_t)n * 32 + (kk >> 2) + k4];
          const float4 qv = reinterpret_cast<const float4*>(Q)[(size_t)j * 32 + (kk >> 2) + k4];
          hv.x = pv.x + qv.x; hv.y = pv.y + qv.y; hv.z = pv.z + qv.z; hv.w = pv.w + qv.w;
        } else {
          hv = reinterpret_cast<const float4*>(big)[e * 32 + (kk >> 2) + k4];
        }
        A_lds[k4 * 4 + 0][m] = fmaxf(fmaf(av.x, hv.x, cv.x), 0.0f);
        A_lds[k4 * 4 + 1][m] = fmaxf(fmaf(av.y, hv.y, cv.y), 0.0f);
        A_lds[k4 * 4 + 2][m] = fmaxf(fmaf(av.z, hv.z, cv.z), 0.0f);
        A_lds[k4 * 4 + 3][m] = fmaxf(fmaf(av.w, hv.w, cv.w), 0.0f);
      }
    }
    {
      const int f4c = tid & 31;
      const int rb = tid >> 5;
#pragma unroll
      for (int p = 0; p < 4; ++p) {
        const int r = p * 8 + rb;
        const float4 wv = reinterpret_cast<const float4*>(Wg)[(size_t)(kk + r) * 32 + f4c];
        *reinterpret_cast<float4*>(&B_lds[r][f4c * 4]) = wv;
      }
    }
    __syncthreads();
#pragma unroll 4
    for (int k = 0; k < 32; ++k) {
      const float4 a0 = *reinterpret_cast<const float4*>(&A_lds[k][tm * 4]);
      const float4 a1 = *reinterpret_cast<const float4*>(&A_lds[k][64 + tm * 4]);
      const float4 b0 = *reinterpret_cast<const float4*>(&B_lds[k][tn * 4]);
      const float4 b1 = *reinterpret_cast<const float4*>(&B_lds[k][64 + tn * 4]);
      const float avv[2][4] = {{a0.x, a0.y, a0.z, a0.w}, {a1.x, a1.y, a1.z, a1.w}};
      const float bvv[2][4] = {{b0.x, b0.y, b0.z, b0.w}, {b1.x, b1.y, b1.z, b1.w}};
#pragma unroll
      for (int rh = 0; rh < 2; ++rh)
#pragma unroll
        for (int a = 0; a < 4; ++a)
#pragma unroll
          for (int ch = 0; ch < 2; ++ch)
#pragma unroll
            for (int b = 0; b < 4; ++b)
              acc[rh][ch][a][b] = fmaf(avv[rh][a], bvv[ch][b], acc[rh][ch][a][b]);
    }
  }

  __syncthreads();
  float sumf[2][4] = {{0, 0, 0, 0}, {0, 0, 0, 0}};
  float sqf[2][4]  = {{0, 0, 0, 0}, {0, 0, 0, 0}};
  const float4 bbl = reinterpret_cast<const float4*>(bias)[tn];
  const float4 bbh = reinterpret_cast<const float4*>(bias)[16 + tn];
  const float bb[2][4] = {{bbl.x, bbl.y, bbl.z, bbl.w}, {bbh.x, bbh.y, bbh.z, bbh.w}};
#pragma unroll
  for (int rh = 0; rh < 2; ++rh) {
#pragma unroll
    for (int a = 0; a < 4; ++a) {
      const size_t e = e0 + rh * 64 + tm * 4 + a;
#pragma unroll
      for (int ch = 0; ch < 2; ++ch) {
        float v[4];
#pragma unroll
        for (int b = 0; b < 4; ++b) {
          v[b] = acc[rh][ch][a][b] + bb[ch][b];
          sumf[ch][b] += v[b];
          sqf[ch][b] = fmaf(v[b], v[b], sqf[ch][b]);
        }
        float4 vv; vv.x = v[0]; vv.y = v[1]; vv.z = v[2]; vv.w = v[3];
        reinterpret_cast<float4*>(big)[e * 32 + ch * 16 + tn] = vv;
      }
    }
  }
  float* sds = reinterpret_cast<float*>(&A_lds[0][0]);
  float* sdq = reinterpret_cast<float*>(&B_lds[0][0]);
#pragma unroll
  for (int ch = 0; ch < 2; ++ch)
#pragma unroll
    for (int b = 0; b < 4; ++b) {
      sds[tm * 128 + ch * 64 + tn * 4 + b] = sumf[ch][b];
      sdq[tm * 128 + ch * 64 + tn * 4 + b] = sqf[ch][b];
    }
  __syncthreads();
  if (tid < 128) {
    double s = 0.0, q = 0.0;
#pragma unroll
    for (int m2 = 0; m2 < 16; ++m2) {
      s += (double)sds[m2 * 128 + tid];
      q += (double)sdq[m2 * 128 + tid];
    }
    psum[(size_t)blockIdx.x * 128 + tid] = s;
    psq[(size_t)blockIdx.x * 128 + tid]  = q;
  }
}

// ---------------------------------------------------------------- final BN+ReLU+sum over K
__global__ __launch_bounds__(256)
void k_final(const float* __restrict__ big, const float* __restrict__ a3,
             const float* __restrict__ c3, float* __restrict__ out) {
  const int t = threadIdx.x;
  const int h = t & 127, ns = t >> 7;
  const size_t n = (size_t)blockIdx.x * 2 + ns;
  const float aa = a3[h], cc = c3[h];
  float s = 0.0f;
#pragma unroll
  for (int k = 0; k < KNN; ++k) {
    const float x = big[(n * KNN + k) * HDIM + h];
    s += fmaxf(fmaf(aa, x, cc), 0.0f);
  }
  out[n * HDIM + h] = s;
}

// ---------------------------------------------------------------- launch
extern "C" void kernel_launch(void* const* d_in, const int* in_sizes, int n_in,
                              void* d_out, int out_size, void* d_ws, size_t ws_size,
                              hipStream_t stream) {
  (void)in_sizes; (void)n_in; (void)out_size;
  const float* X   = (const float*)d_in[0];
  const float* W1  = (const float*)d_in[1];
  const float* b1  = (const float*)d_in[2];
  const float* g1  = (const float*)d_in[3];
  const float* be1 = (const float*)d_in[4];
  const float* W2  = (const float*)d_in[5];
  const float* b2  = (const float*)d_in[6];
  const float* g2  = (const float*)d_in[7];
  const float* be2 = (const float*)d_in[8];
  const float* W3  = (const float*)d_in[9];
  const float* b3  = (const float*)d_in[10];
  const float* g3  = (const float*)d_in[11];
  const float* be3 = (const float*)d_in[12];
  float* out = (float*)d_out;

  char* w = (char*)d_ws;
  size_t off = 0;
  auto carve = [&](size_t bytes) -> char* {
    char* p = w + off;
    off = (off + bytes + 255) & ~(size_t)255;
    return p;
  };
  float*  n2   = (float*)carve((size_t)N_PTS * 4);
  unsigned short* Xh = (unsigned short*)carve((size_t)N_PTS * FDIM * 2);
  unsigned short* Xl = (unsigned short*)carve((size_t)N_PTS * FDIM * 2);
  float*  P    = (float*)carve((size_t)N_PTS * HDIM * 4);
  float*  Q    = (float*)carve((size_t)N_PTS * HDIM * 4);
  int*    knn  = (int*)carve((size_t)NEDGE * 4);
  double* ps1  = (double*)carve((size_t)2048 * 128 * 8);
  double* pq1  = (double*)carve((size_t)2048 * 128 * 8);
  double* ps2  = (double*)carve((size_t)2048 * 128 * 8);
  double* pq2  = (double*)carve((size_t)2048 * 128 * 8);
  double* ps3  = (double*)carve((size_t)2048 * 128 * 8);
  double* pq3  = (double*)carve((size_t)2048 * 128 * 8);
  float*  a1   = (float*)carve(512);
  float*  c1   = (float*)carve(512);
  float*  a2   = (float*)carve(512);
  float*  c2   = (float*)carve(512);
  float*  a3   = (float*)carve(512);
  float*  c3   = (float*)carve(512);
  float*  big  = (float*)carve((size_t)NEDGE * HDIM * 4);
  if (off > ws_size) return;

  k_norms<<<dim3(N_PTS / 256), dim3(256), 0, stream>>>(X, n2);
  k_split<<<dim3(512), dim3(256), 0, stream>>>(X, Xh, Xl);
  k_pq<<<dim3(N_PTS / 8), dim3(256), 0, stream>>>(X, W1, b1, P, Q);
  k_dist_mfma<<<dim3(N_PTS / 32), dim3(512), 0, stream>>>(X, Xh, Xl, n2, knn);
  k_stats_edges<<<dim3(2048), dim3(256), 0, stream>>>(P, Q, knn, ps1, pq1);
  k_reduce_stats<<<dim3(128), dim3(256), 0, stream>>>(ps1, pq1, g1, be1, a1, c1);
  k_gemm<2><<<dim3(NEDGE / 128), dim3(256), 0, stream>>>(P, Q, knn, big, W2, b2, a1, c1, ps2, pq2);
  k_reduce_stats<<<dim3(128), dim3(256), 0, stream>>>(ps2, pq2, g2, be2, a2, c2);
  k_gemm<3><<<dim3(NEDGE / 128), dim3(256), 0, stream>>>(P, Q, knn, big, W3, b3, a2, c2, ps3, pq3);
  k_reduce_stats<<<dim3(128), dim3(256), 0, stream>>>(ps3, pq3, g3, be3, a3, c3);
  k_final<<<dim3(N_PTS / 2), dim3(256), 0, stream>>>(big, a3, c3, out);
}

// Round 10
// 1476.477 us; speedup vs baseline: 1.0557x; 1.0557x over previous
//
#include <hip/hip_runtime.h>

// EdgeConv block. Round 10: occupancy via GRID j-split, not launch-bounds.
// r9 lesson: __launch_bounds__(512,4) -> VGPR 84->64 + 287MB scratch WRITE_SIZE (spill storm).
// Fix: keep r8's proven kernel body (256thr/4waves/84VGPR/no spill), grid 1024 =
// 512 i-tiles x 2 j-halves -> 4 blocks/CU = 16 waves/CU. Each block writes exact
// sorted top-16 (u64 keys) of its j-half; k_merge2 merges the two halves per i.

#define N_PTS 16384
#define FDIM  64
#define HDIM  128
#define KNN   16
#define NEDGE (N_PTS * KNN)

#define SENT_KEY 0xFF800000FFFFFFFFull
#define MAXU64   0xFFFFFFFFFFFFFFFFull
#define EPS_MARGIN 1.0f

typedef __attribute__((ext_vector_type(8)))  short bf16x8;
typedef __attribute__((ext_vector_type(16))) float f32x16;

// ---------------------------------------------------------------- norms
__global__ __launch_bounds__(256)
void k_norms(const float* __restrict__ X, float* __restrict__ n2) {
  const int r = blockIdx.x * 256 + threadIdx.x;
  const float4* x4 = reinterpret_cast<const float4*>(X) + (size_t)r * (FDIM / 4);
  float p[16];
#pragma unroll
  for (int i = 0; i < 16; ++i) {
    const float4 v = x4[i];
    p[i] = (v.x * v.x + v.y * v.y) + (v.z * v.z + v.w * v.w);
  }
#pragma unroll
  for (int s = 1; s < 16; s <<= 1) {
#pragma unroll
    for (int i = 0; i < 16; i += 2 * s) p[i] += p[i + s];
  }
  n2[r] = p[0];
}

// ---------------------------------------------------------------- bf16 hi/lo split of X
__global__ __launch_bounds__(256)
void k_split(const float* __restrict__ X, unsigned short* __restrict__ Xh,
             unsigned short* __restrict__ Xl) {
  const int t = blockIdx.x * 256 + threadIdx.x;           // 8 elems per thread
  const float4* X4 = reinterpret_cast<const float4*>(X);
  const float4 v0 = X4[(size_t)t * 2];
  const float4 v1 = X4[(size_t)t * 2 + 1];
  const float xs[8] = {v0.x, v0.y, v0.z, v0.w, v1.x, v1.y, v1.z, v1.w};
  unsigned int h[8], l[8];
#pragma unroll
  for (int e = 0; e < 8; ++e) {
    const unsigned int u = __float_as_uint(xs[e]);
    h[e] = (u + 0x7FFFu + ((u >> 16) & 1u)) >> 16;        // bf16 RNE
    const float hf = __uint_as_float(h[e] << 16);
    const float r = xs[e] - hf;                            // exact (Sterbenz)
    const unsigned int v = __float_as_uint(r);
    l[e] = (v + 0x7FFFu + ((v >> 16) & 1u)) >> 16;
  }
  uint4 hw, lw;
  hw.x = h[0] | (h[1] << 16); hw.y = h[2] | (h[3] << 16);
  hw.z = h[4] | (h[5] << 16); hw.w = h[6] | (h[7] << 16);
  lw.x = l[0] | (l[1] << 16); lw.y = l[2] | (l[3] << 16);
  lw.z = l[4] | (l[5] << 16); lw.w = l[6] | (l[7] << 16);
  reinterpret_cast<uint4*>(Xh)[t] = hw;
  reinterpret_cast<uint4*>(Xl)[t] = lw;
}

// ---------------------------------------------------------------- P,Q
__global__ __launch_bounds__(256)
void k_pq(const float* __restrict__ X, const float* __restrict__ W1,
          const float* __restrict__ b1, float* __restrict__ P, float* __restrict__ Q) {
  const int h4 = threadIdx.x & 31;
  const int rsub = threadIdx.x >> 5;
  const int row = blockIdx.x * 8 + rsub;
  const float* x = X + (size_t)row * FDIM;
  const float4* W14 = reinterpret_cast<const float4*>(W1);
  float4 at = make_float4(0.f, 0.f, 0.f, 0.f);
  float4 ab = make_float4(0.f, 0.f, 0.f, 0.f);
#pragma unroll 8
  for (int f = 0; f < FDIM; ++f) {
    const float xv = x[f];
    const float4 wt = W14[(size_t)f * 32 + h4];
    const float4 wb = W14[(size_t)(FDIM + f) * 32 + h4];
    at.x = fmaf(xv, wt.x, at.x); at.y = fmaf(xv, wt.y, at.y);
    at.z = fmaf(xv, wt.z, at.z); at.w = fmaf(xv, wt.w, at.w);
    ab.x = fmaf(xv, wb.x, ab.x); ab.y = fmaf(xv, wb.y, ab.y);
    ab.z = fmaf(xv, wb.z, ab.z); ab.w = fmaf(xv, wb.w, ab.w);
  }
  const float4 bb = reinterpret_cast<const float4*>(b1)[h4];
  float4 pv;
  pv.x = at.x - ab.x + bb.x; pv.y = at.y - ab.y + bb.y;
  pv.z = at.z - ab.z + bb.z; pv.w = at.w - ab.w + bb.w;
  reinterpret_cast<float4*>(P)[(size_t)row * 32 + h4] = pv;
  reinterpret_cast<float4*>(Q)[(size_t)row * 32 + h4] = ab;
}

// ---------------------------------------------------------------- MFMA distance + top-16 (per j-half)
// Grid 1024: block = (i-tile it = bx>>1, j-half = bx&1). 256 thr = 4 waves, i-tile 32 rows.
// Wave w scans its half's j-chunks: jb = half*8192 + (ct*4+w)*32, ct<64.
// Body identical to the r8-validated kernel (84 VGPR, no spill). Output: exact sorted
// top-16 u64 keys of this half -> part[i][half][16]; k_merge2 finishes.
// LDS: Xi fp32 [32][64] swz @0 (8KB); thr [8][32] @8192 (1KB); ring u32 [6][256] @9216 (6KB);
//      merge mb u64 [32][8][16] aliases all (32KB).
__global__ __launch_bounds__(256, 2)
void k_dist_mfma(const float* __restrict__ X, const unsigned short* __restrict__ Xh,
                 const unsigned short* __restrict__ Xl, const float* __restrict__ n2g,
                 unsigned long long* __restrict__ part) {
  __shared__ __align__(16) char smem[32768];
  float* Xi = reinterpret_cast<float*>(smem);                    // [32][64] swizzled
  float* thr = reinterpret_cast<float*>(smem + 8192);            // [8][32]
  unsigned int* ring = reinterpret_cast<unsigned int*>(smem + 9216); // [6][256]

  const int tid = threadIdx.x;
  const int w = tid >> 6, lane = tid & 63;
  const int li = lane & 31, hf = lane >> 5;
  const int it = blockIdx.x >> 1;
  const int half = blockIdx.x & 1;
  const int i0 = it * 32;
  const int j0 = half * 8192;
  const int slot = w * 2 + hf;

  const float4* X4 = reinterpret_cast<const float4*>(X);

  thr[tid] = __int_as_float(0x7f800000);
  // stage Xi fp32, swizzled for the exact-recompute reads
  for (int u = tid; u < 512; u += 256) {
    const int row = u >> 4, c4 = u & 15;
    const float4 v = X4[(size_t)(i0 + row) * 16 + c4];
    *reinterpret_cast<float4*>(&Xi[row * 64 + ((c4 ^ (row & 15)) * 4)]) = v;
  }

  // persistent B-frags (Xi hi/lo), lane supplies col li, k = s*16 + hf*8 + e
  bf16x8 bh[4], bl[4];
#pragma unroll
  for (int s = 0; s < 4; ++s) {
    const size_t o = (size_t)(i0 + li) * 64 + s * 16 + hf * 8;
    bh[s] = *reinterpret_cast<const bf16x8*>(Xh + o);
    bl[s] = *reinterpret_cast<const bf16x8*>(Xl + o);
  }
  const float n2i = n2g[i0 + li];

  unsigned long long list[16];
#pragma unroll
  for (int p = 0; p < 16; ++p) list[p] = SENT_KEY;
  int cnt = 0;
  float thrm = __int_as_float(0x7f800000);

  __syncthreads();

  auto flush = [&]() {
#pragma unroll 1
    for (int s = 0; s < 6; ++s) {
      if (s < cnt) {
        const unsigned int j = ring[s * 256 + tid];
        float a = 0.0f;
        const float4* xj4 = reinterpret_cast<const float4*>(X + (size_t)j * 64);
#pragma unroll
        for (int c4 = 0; c4 < 16; ++c4) {   // EXACT r2 fmaf chain, f ascending
          const float4 xiv =
              *reinterpret_cast<const float4*>(&Xi[li * 64 + ((c4 ^ (li & 15)) * 4)]);
          const float4 xjv = xj4[c4];
          a = fmaf(xiv.x, xjv.x, a); a = fmaf(xiv.y, xjv.y, a);
          a = fmaf(xiv.z, xjv.z, a); a = fmaf(xiv.w, xjv.w, a);
        }
        const float t = n2i + n2g[j];
        const float sd = __fsub_rn(t, __fmul_rn(2.0f, a));
        unsigned int ub = __float_as_uint(sd);
        ub = (ub & 0x80000000u) ? ~ub : (ub | 0x80000000u);
        const unsigned long long key = ((unsigned long long)ub << 32) | j;
        if (key < list[15]) {
#pragma unroll
          for (int q = 15; q >= 1; --q) {
            const unsigned long long prev = list[q - 1];
            unsigned long long cur = list[q];
            cur = (key < cur) ? key : cur;
            list[q] = (key < prev) ? prev : cur;
          }
          list[0] = (key < list[0]) ? key : list[0];
        }
      }
    }
    cnt = 0;
    const unsigned int ub16 = (unsigned int)(list[15] >> 32);
    const float tf = (ub16 & 0x80000000u) ? __uint_as_float(ub16 & 0x7fffffffu)
                                          : __uint_as_float(~ub16);
    thr[slot * 32 + li] = tf;
    thrm = fminf(thrm, tf);
  };

  for (int ct = 0; ct < 64; ++ct) {
    const int jb = j0 + (ct * 4 + w) * 32;
    if ((ct & 3) == 0) {  // refresh shared threshold (stale = larger = safe)
      float m = thr[li];
#pragma unroll
      for (int q = 1; q < 8; ++q) m = fminf(m, thr[q * 32 + li]);
      thrm = m;
    }
    bf16x8 ah[4], al[4];
#pragma unroll
    for (int s = 0; s < 4; ++s) {
      const size_t o = (size_t)(jb + li) * 64 + s * 16 + hf * 8;
      ah[s] = *reinterpret_cast<const bf16x8*>(Xh + o);
      al[s] = *reinterpret_cast<const bf16x8*>(Xl + o);
    }
    float4 nj[4];
#pragma unroll
    for (int q = 0; q < 4; ++q)
      nj[q] = *reinterpret_cast<const float4*>(n2g + jb + q * 8 + hf * 4);

    f32x16 acc0 = {0,0,0,0,0,0,0,0,0,0,0,0,0,0,0,0};
    f32x16 acc1 = {0,0,0,0,0,0,0,0,0,0,0,0,0,0,0,0};
#pragma unroll
    for (int s = 0; s < 4; ++s) {
      acc0 = __builtin_amdgcn_mfma_f32_32x32x16_bf16(ah[s], bh[s], acc0, 0, 0, 0);
      acc1 = __builtin_amdgcn_mfma_f32_32x32x16_bf16(ah[s], bl[s], acc1, 0, 0, 0);
      acc1 = __builtin_amdgcn_mfma_f32_32x32x16_bf16(al[s], bh[s], acc1, 0, 0, 0);
    }

    const float lim = thrm + EPS_MARGIN;
#pragma unroll
    for (int r = 0; r < 16; ++r) {
      const float dot = acc0[r] + acc1[r];
      const float njv = (r & 2) ? ((r & 1) ? nj[r >> 2].w : nj[r >> 2].z)
                                : ((r & 1) ? nj[r >> 2].y : nj[r >> 2].x);
      const float sv = fmaf(-2.0f, dot, n2i + njv);
      if (sv <= lim) {
        ring[cnt * 256 + tid] = (unsigned int)(jb + (r & 3) + 8 * (r >> 2) + 4 * hf);
        ++cnt;
      }
      if ((r & 1) && __any(cnt >= 5)) flush();
    }
  }
  flush();  // drain

  // merge: 8 sorted 16-lists per i -> this half's top 16 -> part[i][half]
  __syncthreads();
  unsigned long long* mb = reinterpret_cast<unsigned long long*>(smem); // 32KB alias
#pragma unroll
  for (int p = 0; p < 16; ++p) mb[((size_t)li * 8 + slot) * 16 + p] = list[p];
  __syncthreads();
  if (tid < 32) {
    int pp[8] = {0, 0, 0, 0, 0, 0, 0, 0};
    unsigned long long* dst = part + ((size_t)(i0 + tid) * 2 + half) * 16;
    for (int pick = 0; pick < KNN; ++pick) {
      unsigned long long best = MAXU64; int bq = 0;
#pragma unroll
      for (int q = 0; q < 8; ++q) {
        const unsigned long long cand =
            (pp[q] < 16) ? mb[((size_t)tid * 8 + q) * 16 + pp[q]] : MAXU64;
        if (cand < best) { best = cand; bq = q; }
      }
      pp[bq]++;
      dst[pick] = best;
    }
  }
}

// ---------------------------------------------------------------- merge two sorted half-lists
__global__ __launch_bounds__(256)
void k_merge2(const unsigned long long* __restrict__ part, int* __restrict__ knn) {
  const int i = blockIdx.x * 256 + threadIdx.x;
  const unsigned long long* a = part + (size_t)i * 32;   // half 0, sorted
  const unsigned long long* b = a + 16;                  // half 1, sorted
  int pa = 0, pb = 0;
#pragma unroll
  for (int k = 0; k < KNN; ++k) {
    const unsigned long long va = a[pa];
    const unsigned long long vb = b[pb];
    const bool ta = (va <= vb);
    knn[(size_t)i * KNN + k] = (int)(unsigned int)((ta ? va : vb) & 0xFFFFFFFFULL);
    pa += ta ? 1 : 0;
    pb += ta ? 0 : 1;
  }
}

// ---------------------------------------------------------------- stats of pre1
__global__ __launch_bounds__(256)
void k_stats_edges(const float* __restrict__ P, const float* __restrict__ Q,
                   const int* __restrict__ idx,
                   double* __restrict__ psum, double* __restrict__ psq) {
  __shared__ double sd[2][128];
  __shared__ double qd[2][128];
  const int t = threadIdx.x;
  const int h = t & 127, half = t >> 7;
  const size_t e0 = (size_t)blockIdx.x * 128;
  double s = 0.0, q = 0.0;
  for (int it = 0; it < 64; ++it) {
    const size_t e = e0 + (size_t)it * 2 + half;
    const int n = (int)(e >> 4);
    const int j = idx[e];
    const float v = P[(size_t)n * HDIM + h] + Q[(size_t)j * HDIM + h];
    s += (double)v;
    q += (double)v * (double)v;
  }
  sd[half][h] = s; qd[half][h] = q;
  __syncthreads();
  if (t < 128) {
    psum[(size_t)blockIdx.x * 128 + t] = sd[0][t] + sd[1][t];
    psq[(size_t)blockIdx.x * 128 + t]  = qd[0][t] + qd[1][t];
  }
}

// ---------------------------------------------------------------- stats reduce -> a,c
__global__ __launch_bounds__(256)
void k_reduce_stats(const double* __restrict__ psum, const double* __restrict__ psq,
                    const float* __restrict__ g, const float* __restrict__ beta,
                    float* __restrict__ aout, float* __restrict__ cout) {
  __shared__ double sbuf[256];
  __shared__ double qbuf[256];
  const int h = blockIdx.x, t = threadIdx.x;
  double s = 0.0, q = 0.0;
  for (int i = t; i < 2048; i += 256) {
    s += psum[(size_t)i * 128 + h];
    q += psq[(size_t)i * 128 + h];
  }
  sbuf[t] = s; qbuf[t] = q;
  __syncthreads();
  for (int st = 128; st > 0; st >>= 1) {
    if (t < st) { sbuf[t] += sbuf[t + st]; qbuf[t] += qbuf[t + st]; }
    __syncthreads();
  }
  if (t == 0) {
    const double cntd = (double)NEDGE;
    const double mu = sbuf[0] / cntd;
    double var = qbuf[0] / cntd - mu * mu;
    if (var < 0.0) var = 0.0;
    const double rs = 1.0 / sqrt(var + 1e-5);
    const double a = (double)g[h] * rs;
    aout[h] = (float)a;
    cout[h] = (float)((double)beta[h] - mu * a);
  }
}

// ---------------------------------------------------------------- GEMM (layers 2 & 3)
template <int MODE>
__global__ __launch_bounds__(256, 2)
void k_gemm(const float* __restrict__ P, const float* __restrict__ Q,
            const int* __restrict__ idx, float* __restrict__ big,
            const float* __restrict__ Wg, const float* __restrict__ bias,
            const float* __restrict__ aff_a, const float* __restrict__ aff_c,
            double* __restrict__ psum, double* __restrict__ psq) {
  __shared__ float A_lds[32][132];
  __shared__ float B_lds[32][132];
  const int tid = threadIdx.x;
  const int tm = tid & 15, tn = tid >> 4;
  const size_t e0 = (size_t)blockIdx.x * 128;

  float acc[2][2][4][4] = {};

  for (int kk = 0; kk < 128; kk += 32) {
    __syncthreads();
    {
      const int k4 = tid & 7;
      const int mrow = tid >> 3;
      const float4 av = reinterpret_cast<const float4*>(aff_a)[(kk >> 2) + k4];
      const float4 cv = reinterpret_cast<const float4*>(aff_c)[(kk >> 2) + k4];
#pragma unroll
      for (int p = 0; p < 4; ++p) {
        const int m = p * 32 + mrow;
        const size_t e = e0 + m;
        float4 hv;
        if (MODE == 2) {
          const int n = (int)(e >> 4);
          const int j = idx[e];
          const float4 pv = reinterpret_cast<const float4*>(P)[(size_t)n * 32 + (kk >> 2) + k4];
          const float4 qv = reinterpret_cast<const float4*>(Q)[(size_t)j * 32 + (kk >> 2) + k4];
          hv.x = pv.x + qv.x; hv.y = pv.y + qv.y; hv.z = pv.z + qv.z; hv.w = pv.w + qv.w;
        } else {
          hv = reinterpret_cast<const float4*>(big)[e * 32 + (kk >> 2) + k4];
        }
        A_lds[k4 * 4 + 0][m] = fmaxf(fmaf(av.x, hv.x, cv.x), 0.0f);
        A_lds[k4 * 4 + 1][m] = fmaxf(fmaf(av.y, hv.y, cv.y), 0.0f);
        A_lds[k4 * 4 + 2][m] = fmaxf(fmaf(av.z, hv.z, cv.z), 0.0f);
        A_lds[k4 * 4 + 3][m] = fmaxf(fmaf(av.w, hv.w, cv.w), 0.0f);
      }
    }
    {
      const int f4c = tid & 31;
      const int rb = tid >> 5;
#pragma unroll
      for (int p = 0; p < 4; ++p) {
        const int r = p * 8 + rb;
        const float4 wv = reinterpret_cast<const float4*>(Wg)[(size_t)(kk + r) * 32 + f4c];
        *reinterpret_cast<float4*>(&B_lds[r][f4c * 4]) = wv;
      }
    }
    __syncthreads();
#pragma unroll 4
    for (int k = 0; k < 32; ++k) {
      const float4 a0 = *reinterpret_cast<const float4*>(&A_lds[k][tm * 4]);
      const float4 a1 = *reinterpret_cast<const float4*>(&A_lds[k][64 + tm * 4]);
      const float4 b0 = *reinterpret_cast<const float4*>(&B_lds[k][tn * 4]);
      const float4 b1 = *reinterpret_cast<const float4*>(&B_lds[k][64 + tn * 4]);
      const float avv[2][4] = {{a0.x, a0.y, a0.z, a0.w}, {a1.x, a1.y, a1.z, a1.w}};
      const float bvv[2][4] = {{b0.x, b0.y, b0.z, b0.w}, {b1.x, b1.y, b1.z, b1.w}};
#pragma unroll
      for (int rh = 0; rh < 2; ++rh)
#pragma unroll
        for (int a = 0; a < 4; ++a)
#pragma unroll
          for (int ch = 0; ch < 2; ++ch)
#pragma unroll
            for (int b = 0; b < 4; ++b)
              acc[rh][ch][a][b] = fmaf(avv[rh][a], bvv[ch][b], acc[rh][ch][a][b]);
    }
  }

  __syncthreads();
  float sumf[2][4] = {{0, 0, 0, 0}, {0, 0, 0, 0}};
  float sqf[2][4]  = {{0, 0, 0, 0}, {0, 0, 0, 0}};
  const float4 bbl = reinterpret_cast<const float4*>(bias)[tn];
  const float4 bbh = reinterpret_cast<const float4*>(bias)[16 + tn];
  const float bb[2][4] = {{bbl.x, bbl.y, bbl.z, bbl.w}, {bbh.x, bbh.y, bbh.z, bbh.w}};
#pragma unroll
  for (int rh = 0; rh < 2; ++rh) {
#pragma unroll
    for (int a = 0; a < 4; ++a) {
      const size_t e = e0 + rh * 64 + tm * 4 + a;
#pragma unroll
      for (int ch = 0; ch < 2; ++ch) {
        float v[4];
#pragma unroll
        for (int b = 0; b < 4; ++b) {
          v[b] = acc[rh][ch][a][b] + bb[ch][b];
          sumf[ch][b] += v[b];
          sqf[ch][b] = fmaf(v[b], v[b], sqf[ch][b]);
        }
        float4 vv; vv.x = v[0]; vv.y = v[1]; vv.z = v[2]; vv.w = v[3];
        reinterpret_cast<float4*>(big)[e * 32 + ch * 16 + tn] = vv;
      }
    }
  }
  float* sds = reinterpret_cast<float*>(&A_lds[0][0]);
  float* sdq = reinterpret_cast<float*>(&B_lds[0][0]);
#pragma unroll
  for (int ch = 0; ch < 2; ++ch)
#pragma unroll
    for (int b = 0; b < 4; ++b) {
      sds[tm * 128 + ch * 64 + tn * 4 + b] = sumf[ch][b];
      sdq[tm * 128 + ch * 64 + tn * 4 + b] = sqf[ch][b];
    }
  __syncthreads();
  if (tid < 128) {
    double s = 0.0, q = 0.0;
#pragma unroll
    for (int m2 = 0; m2 < 16; ++m2) {
      s += (double)sds[m2 * 128 + tid];
      q += (double)sdq[m2 * 128 + tid];
    }
    psum[(size_t)blockIdx.x * 128 + tid] = s;
    psq[(size_t)blockIdx.x * 128 + tid]  = q;
  }
}

// ---------------------------------------------------------------- final BN+ReLU+sum over K
__global__ __launch_bounds__(256)
void k_final(const float* __restrict__ big, const float* __restrict__ a3,
             const float* __restrict__ c3, float* __restrict__ out) {
  const int t = threadIdx.x;
  const int h = t & 127, ns = t >> 7;
  const size_t n = (size_t)blockIdx.x * 2 + ns;
  const float aa = a3[h], cc = c3[h];
  float s = 0.0f;
#pragma unroll
  for (int k = 0; k < KNN; ++k) {
    const float x = big[(n * KNN + k) * HDIM + h];
    s += fmaxf(fmaf(aa, x, cc), 0.0f);
  }
  out[n * HDIM + h] = s;
}

// ---------------------------------------------------------------- launch
extern "C" void kernel_launch(void* const* d_in, const int* in_sizes, int n_in,
                              void* d_out, int out_size, void* d_ws, size_t ws_size,
                              hipStream_t stream) {
  (void)in_sizes; (void)n_in; (void)out_size;
  const float* X   = (const float*)d_in[0];
  const float* W1  = (const float*)d_in[1];
  const float* b1  = (const float*)d_in[2];
  const float* g1  = (const float*)d_in[3];
  const float* be1 = (const float*)d_in[4];
  const float* W2  = (const float*)d_in[5];
  const float* b2  = (const float*)d_in[6];
  const float* g2  = (const float*)d_in[7];
  const float* be2 = (const float*)d_in[8];
  const float* W3  = (const float*)d_in[9];
  const float* b3  = (const float*)d_in[10];
  const float* g3  = (const float*)d_in[11];
  const float* be3 = (const float*)d_in[12];
  float* out = (float*)d_out;

  char* w = (char*)d_ws;
  size_t off = 0;
  auto carve = [&](size_t bytes) -> char* {
    char* p = w + off;
    off = (off + bytes + 255) & ~(size_t)255;
    return p;
  };
  float*  n2   = (float*)carve((size_t)N_PTS * 4);
  unsigned short* Xh = (unsigned short*)carve((size_t)N_PTS * FDIM * 2);
  unsigned short* Xl = (unsigned short*)carve((size_t)N_PTS * FDIM * 2);
  float*  P    = (float*)carve((size_t)N_PTS * HDIM * 4);
  float*  Q    = (float*)carve((size_t)N_PTS * HDIM * 4);
  int*    knn  = (int*)carve((size_t)NEDGE * 4);
  unsigned long long* part = (unsigned long long*)carve((size_t)N_PTS * 32 * 8);
  double* ps1  = (double*)carve((size_t)2048 * 128 * 8);
  double* pq1  = (double*)carve((size_t)2048 * 128 * 8);
  double* ps2  = (double*)carve((size_t)2048 * 128 * 8);
  double* pq2  = (double*)carve((size_t)2048 * 128 * 8);
  double* ps3  = (double*)carve((size_t)2048 * 128 * 8);
  double* pq3  = (double*)carve((size_t)2048 * 128 * 8);
  float*  a1   = (float*)carve(512);
  float*  c1   = (float*)carve(512);
  float*  a2   = (float*)carve(512);
  float*  c2   = (float*)carve(512);
  float*  a3   = (float*)carve(512);
  float*  c3   = (float*)carve(512);
  float*  big  = (float*)carve((size_t)NEDGE * HDIM * 4);
  if (off > ws_size) return;

  k_norms<<<dim3(N_PTS / 256), dim3(256), 0, stream>>>(X, n2);
  k_split<<<dim3(512), dim3(256), 0, stream>>>(X, Xh, Xl);
  k_pq<<<dim3(N_PTS / 8), dim3(256), 0, stream>>>(X, W1, b1, P, Q);
  k_dist_mfma<<<dim3(N_PTS / 32 * 2), dim3(256), 0, stream>>>(X, Xh, Xl, n2, part);
  k_merge2<<<dim3(N_PTS / 256), dim3(256), 0, stream>>>(part, knn);
  k_stats_edges<<<dim3(2048), dim3(256), 0, stream>>>(P, Q, knn, ps1, pq1);
  k_reduce_stats<<<dim3(128), dim3(256), 0, stream>>>(ps1, pq1, g1, be1, a1, c1);
  k_gemm<2><<<dim3(NEDGE / 128), dim3(256), 0, stream>>>(P, Q, knn, big, W2, b2, a1, c1, ps2, pq2);
  k_reduce_stats<<<dim3(128), dim3(256), 0, stream>>>(ps2, pq2, g2, be2, a2, c2);
  k_gemm<3><<<dim3(NEDGE / 128), dim3(256), 0, stream>>>(P, Q, knn, big, W3, b3, a2, c2, ps3, pq3);
  k_reduce_stats<<<dim3(128), dim3(256), 0, stream>>>(ps3, pq3, g3, be3, a3, c3);
  k_final<<<dim3(N_PTS / 2), dim3(256), 0, stream>>>(big, a3, c3, out);
}

// Round 11
// 1253.812 us; speedup vs baseline: 1.2432x; 1.1776x over previous
//
#include <hip/hip_runtime.h>

// EdgeConv block. Round 11.
// r10 natural experiment: dur = r8_base(260) + 2x flush(500) exactly -> exact-flush path
// dominates; occupancy pinned ~2 blocks/CU regardless of grid.
// Changes: (1) flush chain 4-way split (serial 256->~70cyc); (2) margin 1.0->0.0625
// (60x safety vs ~1e-3 approx error); (3) j-split x2 with GLOBAL atomicMin threshold
// sharing (kills r10's threshold-degradation mechanism); (4) live-LDS 15.3KB, slot
// lists written directly to global part (aliased on big), k_merge does 16-way merge.

#define N_PTS 16384
#define FDIM  64
#define HDIM  128
#define KNN   16
#define NEDGE (N_PTS * KNN)

#define SENT_KEY 0xFF800000FFFFFFFFull
#define MAXU64   0xFFFFFFFFFFFFFFFFull
#define EPS_MARGIN 0.0625f

typedef __attribute__((ext_vector_type(8)))  short bf16x8;
typedef __attribute__((ext_vector_type(16))) float f32x16;

__device__ __forceinline__ unsigned int enc_f(float f) {
  unsigned int u = __float_as_uint(f);
  return (u & 0x80000000u) ? ~u : (u | 0x80000000u);
}
__device__ __forceinline__ float dec_f(unsigned int e) {
  return (e & 0x80000000u) ? __uint_as_float(e & 0x7fffffffu) : __uint_as_float(~e);
}

// ---------------------------------------------------------------- norms
__global__ __launch_bounds__(256)
void k_norms(const float* __restrict__ X, float* __restrict__ n2) {
  const int r = blockIdx.x * 256 + threadIdx.x;
  const float4* x4 = reinterpret_cast<const float4*>(X) + (size_t)r * (FDIM / 4);
  float p[16];
#pragma unroll
  for (int i = 0; i < 16; ++i) {
    const float4 v = x4[i];
    p[i] = (v.x * v.x + v.y * v.y) + (v.z * v.z + v.w * v.w);
  }
#pragma unroll
  for (int s = 1; s < 16; s <<= 1) {
#pragma unroll
    for (int i = 0; i < 16; i += 2 * s) p[i] += p[i + s];
  }
  n2[r] = p[0];
}

// ---------------------------------------------------------------- bf16 hi/lo split + thrG init
__global__ __launch_bounds__(256)
void k_split(const float* __restrict__ X, unsigned short* __restrict__ Xh,
             unsigned short* __restrict__ Xl, unsigned int* __restrict__ thrG) {
  const int t = blockIdx.x * 256 + threadIdx.x;           // 8 elems per thread
  if (t < N_PTS) thrG[t] = 0xFF800000u;                   // enc(+inf)
  const float4* X4 = reinterpret_cast<const float4*>(X);
  const float4 v0 = X4[(size_t)t * 2];
  const float4 v1 = X4[(size_t)t * 2 + 1];
  const float xs[8] = {v0.x, v0.y, v0.z, v0.w, v1.x, v1.y, v1.z, v1.w};
  unsigned int h[8], l[8];
#pragma unroll
  for (int e = 0; e < 8; ++e) {
    const unsigned int u = __float_as_uint(xs[e]);
    h[e] = (u + 0x7FFFu + ((u >> 16) & 1u)) >> 16;        // bf16 RNE
    const float hf = __uint_as_float(h[e] << 16);
    const float r = xs[e] - hf;                            // exact (Sterbenz)
    const unsigned int v = __float_as_uint(r);
    l[e] = (v + 0x7FFFu + ((v >> 16) & 1u)) >> 16;
  }
  uint4 hw, lw;
  hw.x = h[0] | (h[1] << 16); hw.y = h[2] | (h[3] << 16);
  hw.z = h[4] | (h[5] << 16); hw.w = h[6] | (h[7] << 16);
  lw.x = l[0] | (l[1] << 16); lw.y = l[2] | (l[3] << 16);
  lw.z = l[4] | (l[5] << 16); lw.w = l[6] | (l[7] << 16);
  reinterpret_cast<uint4*>(Xh)[t] = hw;
  reinterpret_cast<uint4*>(Xl)[t] = lw;
}

// ---------------------------------------------------------------- P,Q
__global__ __launch_bounds__(256)
void k_pq(const float* __restrict__ X, const float* __restrict__ W1,
          const float* __restrict__ b1, float* __restrict__ P, float* __restrict__ Q) {
  const int h4 = threadIdx.x & 31;
  const int rsub = threadIdx.x >> 5;
  const int row = blockIdx.x * 8 + rsub;
  const float* x = X + (size_t)row * FDIM;
  const float4* W14 = reinterpret_cast<const float4*>(W1);
  float4 at = make_float4(0.f, 0.f, 0.f, 0.f);
  float4 ab = make_float4(0.f, 0.f, 0.f, 0.f);
#pragma unroll 8
  for (int f = 0; f < FDIM; ++f) {
    const float xv = x[f];
    const float4 wt = W14[(size_t)f * 32 + h4];
    const float4 wb = W14[(size_t)(FDIM + f) * 32 + h4];
    at.x = fmaf(xv, wt.x, at.x); at.y = fmaf(xv, wt.y, at.y);
    at.z = fmaf(xv, wt.z, at.z); at.w = fmaf(xv, wt.w, at.w);
    ab.x = fmaf(xv, wb.x, ab.x); ab.y = fmaf(xv, wb.y, ab.y);
    ab.z = fmaf(xv, wb.z, ab.z); ab.w = fmaf(xv, wb.w, ab.w);
  }
  const float4 bb = reinterpret_cast<const float4*>(b1)[h4];
  float4 pv;
  pv.x = at.x - ab.x + bb.x; pv.y = at.y - ab.y + bb.y;
  pv.z = at.z - ab.z + bb.z; pv.w = at.w - ab.w + bb.w;
  reinterpret_cast<float4*>(P)[(size_t)row * 32 + h4] = pv;
  reinterpret_cast<float4*>(Q)[(size_t)row * 32 + h4] = ab;
}

// ---------------------------------------------------------------- MFMA distance + top-16
// Grid 1024: block = (i-tile = bx>>1, j-half = bx&1); 256 thr = 4 waves; i-tile 32 rows.
// Wave w scans jb = half*8192 + (ct*4+w)*32, ct<64. 3-split bf16 MFMA C[j,i]; lane owns
// i = i0+(lane&31), 16 j-scores in acc regs. Threshold = min(own 8 slots' exact 16th,
// global thrG[i] via atomicMin publish / plain read — stale=larger=safe). Approx filter
// (margin 0.0625 >> 1e-3 err) -> per-thread LDS ring -> ballot-gated exact re-score
// (4-way split fp32 fmaf chain, u64 tie keys). Slot lists written straight to part.
// LDS 15360B: Xi fp32 [32][64] swz @0 (8KB); thr [8][32] @8192 (1KB); ring [6][256] @9216 (6KB).
__global__ __launch_bounds__(256, 2)
void k_dist_mfma(const float* __restrict__ X, const unsigned short* __restrict__ Xh,
                 const unsigned short* __restrict__ Xl, const float* __restrict__ n2g,
                 unsigned int* __restrict__ thrG, unsigned long long* __restrict__ part) {
  __shared__ __align__(16) char smem[15360];
  float* Xi = reinterpret_cast<float*>(smem);                    // [32][64] swizzled
  float* thr = reinterpret_cast<float*>(smem + 8192);            // [8][32]
  unsigned int* ring = reinterpret_cast<unsigned int*>(smem + 9216); // [6][256]

  const int tid = threadIdx.x;
  const int w = tid >> 6, lane = tid & 63;
  const int li = lane & 31, hf = lane >> 5;
  const int it = blockIdx.x >> 1;
  const int half = blockIdx.x & 1;
  const int i0 = it * 32;
  const int j0 = half * 8192;
  const int slot = w * 2 + hf;

  const float4* X4 = reinterpret_cast<const float4*>(X);

  thr[tid] = __int_as_float(0x7f800000);
  // stage Xi fp32, swizzled for the exact-recompute reads
  for (int u = tid; u < 512; u += 256) {
    const int row = u >> 4, c4 = u & 15;
    const float4 v = X4[(size_t)(i0 + row) * 16 + c4];
    *reinterpret_cast<float4*>(&Xi[row * 64 + ((c4 ^ (row & 15)) * 4)]) = v;
  }

  // persistent B-frags (Xi hi/lo), lane supplies col li, k = s*16 + hf*8 + e
  bf16x8 bh[4], bl[4];
#pragma unroll
  for (int s = 0; s < 4; ++s) {
    const size_t o = (size_t)(i0 + li) * 64 + s * 16 + hf * 8;
    bh[s] = *reinterpret_cast<const bf16x8*>(Xh + o);
    bl[s] = *reinterpret_cast<const bf16x8*>(Xl + o);
  }
  const float n2i = n2g[i0 + li];

  unsigned long long list[16];
#pragma unroll
  for (int p = 0; p < 16; ++p) list[p] = SENT_KEY;
  int cnt = 0;
  float thrm = __int_as_float(0x7f800000);

  __syncthreads();

  auto flush = [&]() {
#pragma unroll 1
    for (int s = 0; s < 6; ++s) {
      if (s < cnt) {
        const unsigned int j = ring[s * 256 + tid];
        const float4* xj4 = reinterpret_cast<const float4*>(X + (size_t)j * 64);
        float sa[4] = {0.0f, 0.0f, 0.0f, 0.0f};
#pragma unroll
        for (int g = 0; g < 4; ++g) {   // 4 independent sub-chains (latency ~70cyc)
#pragma unroll
          for (int c4 = g * 4; c4 < g * 4 + 4; ++c4) {
            const float4 xiv =
                *reinterpret_cast<const float4*>(&Xi[li * 64 + ((c4 ^ (li & 15)) * 4)]);
            const float4 xjv = xj4[c4];
            sa[g] = fmaf(xiv.x, xjv.x, sa[g]); sa[g] = fmaf(xiv.y, xjv.y, sa[g]);
            sa[g] = fmaf(xiv.z, xjv.z, sa[g]); sa[g] = fmaf(xiv.w, xjv.w, sa[g]);
          }
        }
        const float a = (sa[0] + sa[1]) + (sa[2] + sa[3]);
        const float t = n2i + n2g[j];
        const float sd = __fsub_rn(t, __fmul_rn(2.0f, a));
        const unsigned long long key = ((unsigned long long)enc_f(sd) << 32) | j;
        if (key < list[15]) {
#pragma unroll
          for (int q = 15; q >= 1; --q) {
            const unsigned long long prev = list[q - 1];
            unsigned long long cur = list[q];
            cur = (key < cur) ? key : cur;
            list[q] = (key < prev) ? prev : cur;
          }
          list[0] = (key < list[0]) ? key : list[0];
        }
      }
    }
    cnt = 0;
    const float tf = dec_f((unsigned int)(list[15] >> 32));
    thr[slot * 32 + li] = tf;
    thrm = fminf(thrm, tf);
  };

  for (int ct = 0; ct < 64; ++ct) {
    const int jb = j0 + (ct * 4 + w) * 32;
    if ((ct & 3) == 0) {  // refresh threshold: own 8 slots (LDS) + global (thrG)
      float m = thr[li];
#pragma unroll
      for (int q = 1; q < 8; ++q) m = fminf(m, thr[q * 32 + li]);
      if (w == 0 && hf == 0 && m < __int_as_float(0x7f800000))
        atomicMin(&thrG[i0 + li], enc_f(m));
      thrm = fminf(m, dec_f(thrG[i0 + li]));   // stale read = larger = safe
    }
    bf16x8 ah[4], al[4];
#pragma unroll
    for (int s = 0; s < 4; ++s) {
      const size_t o = (size_t)(jb + li) * 64 + s * 16 + hf * 8;
      ah[s] = *reinterpret_cast<const bf16x8*>(Xh + o);
      al[s] = *reinterpret_cast<const bf16x8*>(Xl + o);
    }
    float4 nj[4];
#pragma unroll
    for (int q = 0; q < 4; ++q)
      nj[q] = *reinterpret_cast<const float4*>(n2g + jb + q * 8 + hf * 4);

    f32x16 acc0 = {0,0,0,0,0,0,0,0,0,0,0,0,0,0,0,0};
    f32x16 acc1 = {0,0,0,0,0,0,0,0,0,0,0,0,0,0,0,0};
#pragma unroll
    for (int s = 0; s < 4; ++s) {
      acc0 = __builtin_amdgcn_mfma_f32_32x32x16_bf16(ah[s], bh[s], acc0, 0, 0, 0);
      acc1 = __builtin_amdgcn_mfma_f32_32x32x16_bf16(ah[s], bl[s], acc1, 0, 0, 0);
      acc1 = __builtin_amdgcn_mfma_f32_32x32x16_bf16(al[s], bh[s], acc1, 0, 0, 0);
    }

    const float lim = thrm + EPS_MARGIN;
#pragma unroll
    for (int r = 0; r < 16; ++r) {
      const float dot = acc0[r] + acc1[r];
      const float njv = (r & 2) ? ((r & 1) ? nj[r >> 2].w : nj[r >> 2].z)
                                : ((r & 1) ? nj[r >> 2].y : nj[r >> 2].x);
      const float sv = fmaf(-2.0f, dot, n2i + njv);
      if (sv <= lim) {
        ring[cnt * 256 + tid] = (unsigned int)(jb + (r & 3) + 8 * (r >> 2) + 4 * hf);
        ++cnt;
      }
      if ((r & 1) && __any(cnt >= 5)) flush();
    }
  }
  flush();  // drain

  // write this slot's exact sorted 16-list straight to part[i][half*8+slot][16]
  unsigned long long* dst =
      part + (((size_t)(i0 + li)) * 16 + half * 8 + slot) * 16;
#pragma unroll
  for (int p = 0; p < 16; ++p) dst[p] = list[p];
}

// ---------------------------------------------------------------- 16-way merge of sorted lists
__global__ __launch_bounds__(256)
void k_merge(const unsigned long long* __restrict__ part, int* __restrict__ knn) {
  const int i = blockIdx.x * 256 + threadIdx.x;
  const unsigned long long* base = part + (size_t)i * 256;
  int pp[16];
#pragma unroll
  for (int q = 0; q < 16; ++q) pp[q] = 0;
  for (int pick = 0; pick < KNN; ++pick) {
    unsigned long long best = MAXU64; int bq = 0;
#pragma unroll
    for (int q = 0; q < 16; ++q) {
      const unsigned long long cand =
          (pp[q] < 16) ? base[q * 16 + pp[q]] : MAXU64;
      if (cand < best) { best = cand; bq = q; }
    }
    pp[bq]++;
    knn[(size_t)i * KNN + pick] = (int)(unsigned int)(best & 0xFFFFFFFFULL);
  }
}

// ---------------------------------------------------------------- stats of pre1
__global__ __launch_bounds__(256)
void k_stats_edges(const float* __restrict__ P, const float* __restrict__ Q,
                   const int* __restrict__ idx,
                   double* __restrict__ psum, double* __restrict__ psq) {
  __shared__ double sd[2][128];
  __shared__ double qd[2][128];
  const int t = threadIdx.x;
  const int h = t & 127, half = t >> 7;
  const size_t e0 = (size_t)blockIdx.x * 128;
  double s = 0.0, q = 0.0;
  for (int it = 0; it < 64; ++it) {
    const size_t e = e0 + (size_t)it * 2 + half;
    const int n = (int)(e >> 4);
    const int j = idx[e];
    const float v = P[(size_t)n * HDIM + h] + Q[(size_t)j * HDIM + h];
    s += (double)v;
    q += (double)v * (double)v;
  }
  sd[half][h] = s; qd[half][h] = q;
  __syncthreads();
  if (t < 128) {
    psum[(size_t)blockIdx.x * 128 + t] = sd[0][t] + sd[1][t];
    psq[(size_t)blockIdx.x * 128 + t]  = qd[0][t] + qd[1][t];
  }
}

// ---------------------------------------------------------------- stats reduce -> a,c
__global__ __launch_bounds__(256)
void k_reduce_stats(const double* __restrict__ psum, const double* __restrict__ psq,
                    const float* __restrict__ g, const float* __restrict__ beta,
                    float* __restrict__ aout, float* __restrict__ cout) {
  __shared__ double sbuf[256];
  __shared__ double qbuf[256];
  const int h = blockIdx.x, t = threadIdx.x;
  double s = 0.0, q = 0.0;
  for (int i = t; i < 2048; i += 256) {
    s += psum[(size_t)i * 128 + h];
    q += psq[(size_t)i * 128 + h];
  }
  sbuf[t] = s; qbuf[t] = q;
  __syncthreads();
  for (int st = 128; st > 0; st >>= 1) {
    if (t < st) { sbuf[t] += sbuf[t + st]; qbuf[t] += qbuf[t + st]; }
    __syncthreads();
  }
  if (t == 0) {
    const double cntd = (double)NEDGE;
    const double mu = sbuf[0] / cntd;
    double var = qbuf[0] / cntd - mu * mu;
    if (var < 0.0) var = 0.0;
    const double rs = 1.0 / sqrt(var + 1e-5);
    const double a = (double)g[h] * rs;
    aout[h] = (float)a;
    cout[h] = (float)((double)beta[h] - mu * a);
  }
}

// ---------------------------------------------------------------- GEMM (layers 2 & 3)
template <int MODE>
__global__ __launch_bounds__(256, 2)
void k_gemm(const float* __restrict__ P, const float* __restrict__ Q,
            const int* __restrict__ idx, float* __restrict__ big,
            const float* __restrict__ Wg, const float* __restrict__ bias,
            const float* __restrict__ aff_a, const float* __restrict__ aff_c,
            double* __restrict__ psum, double* __restrict__ psq) {
  __shared__ float A_lds[32][132];
  __shared__ float B_lds[32][132];
  const int tid = threadIdx.x;
  const int tm = tid & 15, tn = tid >> 4;
  const size_t e0 = (size_t)blockIdx.x * 128;

  float acc[2][2][4][4] = {};

  for (int kk = 0; kk < 128; kk += 32) {
    __syncthreads();
    {
      const int k4 = tid & 7;
      const int mrow = tid >> 3;
      const float4 av = reinterpret_cast<const float4*>(aff_a)[(kk >> 2) + k4];
      const float4 cv = reinterpret_cast<const float4*>(aff_c)[(kk >> 2) + k4];
#pragma unroll
      for (int p = 0; p < 4; ++p) {
        const int m = p * 32 + mrow;
        const size_t e = e0 + m;
        float4 hv;
        if (MODE == 2) {
          const int n = (int)(e >> 4);
          const int j = idx[e];
          const float4 pv = reinterpret_cast<const float4*>(P)[(size_t)n * 32 + (kk >> 2) + k4];
          const float4 qv = reinterpret_cast<const float4*>(Q)[(size_t)j * 32 + (kk >> 2) + k4];
          hv.x = pv.x + qv.x; hv.y = pv.y + qv.y; hv.z = pv.z + qv.z; hv.w = pv.w + qv.w;
        } else {
          hv = reinterpret_cast<const float4*>(big)[e * 32 + (kk >> 2) + k4];
        }
        A_lds[k4 * 4 + 0][m] = fmaxf(fmaf(av.x, hv.x, cv.x), 0.0f);
        A_lds[k4 * 4 + 1][m] = fmaxf(fmaf(av.y, hv.y, cv.y), 0.0f);
        A_lds[k4 * 4 + 2][m] = fmaxf(fmaf(av.z, hv.z, cv.z), 0.0f);
        A_lds[k4 * 4 + 3][m] = fmaxf(fmaf(av.w, hv.w, cv.w), 0.0f);
      }
    }
    {
      const int f4c = tid & 31;
      const int rb = tid >> 5;
#pragma unroll
      for (int p = 0; p < 4; ++p) {
        const int r = p * 8 + rb;
        const float4 wv = reinterpret_cast<const float4*>(Wg)[(size_t)(kk + r) * 32 + f4c];
        *reinterpret_cast<float4*>(&B_lds[r][f4c * 4]) = wv;
      }
    }
    __syncthreads();
#pragma unroll 4
    for (int k = 0; k < 32; ++k) {
      const float4 a0 = *reinterpret_cast<const float4*>(&A_lds[k][tm * 4]);
      const float4 a1 = *reinterpret_cast<const float4*>(&A_lds[k][64 + tm * 4]);
      const float4 b0 = *reinterpret_cast<const float4*>(&B_lds[k][tn * 4]);
      const float4 b1 = *reinterpret_cast<const float4*>(&B_lds[k][64 + tn * 4]);
      const float avv[2][4] = {{a0.x, a0.y, a0.z, a0.w}, {a1.x, a1.y, a1.z, a1.w}};
      const float bvv[2][4] = {{b0.x, b0.y, b0.z, b0.w}, {b1.x, b1.y, b1.z, b1.w}};
#pragma unroll
      for (int rh = 0; rh < 2; ++rh)
#pragma unroll
        for (int a = 0; a < 4; ++a)
#pragma unroll
          for (int ch = 0; ch < 2; ++ch)
#pragma unroll
            for (int b = 0; b < 4; ++b)
              acc[rh][ch][a][b] = fmaf(avv[rh][a], bvv[ch][b], acc[rh][ch][a][b]);
    }
  }

  __syncthreads();
  float sumf[2][4] = {{0, 0, 0, 0}, {0, 0, 0, 0}};
  float sqf[2][4]  = {{0, 0, 0, 0}, {0, 0, 0, 0}};
  const float4 bbl = reinterpret_cast<const float4*>(bias)[tn];
  const float4 bbh = reinterpret_cast<const float4*>(bias)[16 + tn];
  const float bb[2][4] = {{bbl.x, bbl.y, bbl.z, bbl.w}, {bbh.x, bbh.y, bbh.z, bbh.w}};
#pragma unroll
  for (int rh = 0; rh < 2; ++rh) {
#pragma unroll
    for (int a = 0; a < 4; ++a) {
      const size_t e = e0 + rh * 64 + tm * 4 + a;
#pragma unroll
      for (int ch = 0; ch < 2; ++ch) {
        float v[4];
#pragma unroll
        for (int b = 0; b < 4; ++b) {
          v[b] = acc[rh][ch][a][b] + bb[ch][b];
          sumf[ch][b] += v[b];
          sqf[ch][b] = fmaf(v[b], v[b], sqf[ch][b]);
        }
        float4 vv; vv.x = v[0]; vv.y = v[1]; vv.z = v[2]; vv.w = v[3];
        reinterpret_cast<float4*>(big)[e * 32 + ch * 16 + tn] = vv;
      }
    }
  }
  float* sds = reinterpret_cast<float*>(&A_lds[0][0]);
  float* sdq = reinterpret_cast<float*>(&B_lds[0][0]);
#pragma unroll
  for (int ch = 0; ch < 2; ++ch)
#pragma unroll
    for (int b = 0; b < 4; ++b) {
      sds[tm * 128 + ch * 64 + tn * 4 + b] = sumf[ch][b];
      sdq[tm * 128 + ch * 64 + tn * 4 + b] = sqf[ch][b];
    }
  __syncthreads();
  if (tid < 128) {
    double s = 0.0, q = 0.0;
#pragma unroll
    for (int m2 = 0; m2 < 16; ++m2) {
      s += (double)sds[m2 * 128 + tid];
      q += (double)sdq[m2 * 128 + tid];
    }
    psum[(size_t)blockIdx.x * 128 + tid] = s;
    psq[(size_t)blockIdx.x * 128 + tid]  = q;
  }
}

// ---------------------------------------------------------------- final BN+ReLU+sum over K
__global__ __launch_bounds__(256)
void k_final(const float* __restrict__ big, const float* __restrict__ a3,
             const float* __restrict__ c3, float* __restrict__ out) {
  const int t = threadIdx.x;
  const int h = t & 127, ns = t >> 7;
  const size_t n = (size_t)blockIdx.x * 2 + ns;
  const float aa = a3[h], cc = c3[h];
  float s = 0.0f;
#pragma unroll
  for (int k = 0; k < KNN; ++k) {
    const float x = big[(n * KNN + k) * HDIM + h];
    s += fmaxf(fmaf(aa, x, cc), 0.0f);
  }
  out[n * HDIM + h] = s;
}

// ---------------------------------------------------------------- launch
extern "C" void kernel_launch(void* const* d_in, const int* in_sizes, int n_in,
                              void* d_out, int out_size, void* d_ws, size_t ws_size,
                              hipStream_t stream) {
  (void)in_sizes; (void)n_in; (void)out_size;
  const float* X   = (const float*)d_in[0];
  const float* W1  = (const float*)d_in[1];
  const float* b1  = (const float*)d_in[2];
  const float* g1  = (const float*)d_in[3];
  const float* be1 = (const float*)d_in[4];
  const float* W2  = (const float*)d_in[5];
  const float* b2  = (const float*)d_in[6];
  const float* g2  = (const float*)d_in[7];
  const float* be2 = (const float*)d_in[8];
  const float* W3  = (const float*)d_in[9];
  const float* b3  = (const float*)d_in[10];
  const float* g3  = (const float*)d_in[11];
  const float* be3 = (const float*)d_in[12];
  float* out = (float*)d_out;

  char* w = (char*)d_ws;
  size_t off = 0;
  auto carve = [&](size_t bytes) -> char* {
    char* p = w + off;
    off = (off + bytes + 255) & ~(size_t)255;
    return p;
  };
  float*  n2   = (float*)carve((size_t)N_PTS * 4);
  unsigned short* Xh = (unsigned short*)carve((size_t)N_PTS * FDIM * 2);
  unsigned short* Xl = (unsigned short*)carve((size_t)N_PTS * FDIM * 2);
  unsigned int* thrG = (unsigned int*)carve((size_t)N_PTS * 4);
  float*  P    = (float*)carve((size_t)N_PTS * HDIM * 4);
  float*  Q    = (float*)carve((size_t)N_PTS * HDIM * 4);
  int*    knn  = (int*)carve((size_t)NEDGE * 4);
  double* ps1  = (double*)carve((size_t)2048 * 128 * 8);
  double* pq1  = (double*)carve((size_t)2048 * 128 * 8);
  double* ps2  = (double*)carve((size_t)2048 * 128 * 8);
  double* pq2  = (double*)carve((size_t)2048 * 128 * 8);
  double* ps3  = (double*)carve((size_t)2048 * 128 * 8);
  double* pq3  = (double*)carve((size_t)2048 * 128 * 8);
  float*  a1   = (float*)carve(512);
  float*  c1   = (float*)carve(512);
  float*  a2   = (float*)carve(512);
  float*  c2   = (float*)carve(512);
  float*  a3   = (float*)carve(512);
  float*  c3   = (float*)carve(512);
  float*  big  = (float*)carve((size_t)NEDGE * HDIM * 4);
  if (off > ws_size) return;
  // part aliases big's space (32MB of 128MB): consumed by k_merge before k_gemm writes big
  unsigned long long* part = (unsigned long long*)big;

  k_norms<<<dim3(N_PTS / 256), dim3(256), 0, stream>>>(X, n2);
  k_split<<<dim3(512), dim3(256), 0, stream>>>(X, Xh, Xl, thrG);
  k_pq<<<dim3(N_PTS / 8), dim3(256), 0, stream>>>(X, W1, b1, P, Q);
  k_dist_mfma<<<dim3(N_PTS / 32 * 2), dim3(256), 0, stream>>>(X, Xh, Xl, n2, thrG, part);
  k_merge<<<dim3(N_PTS / 256), dim3(256), 0, stream>>>(part, knn);
  k_stats_edges<<<dim3(2048), dim3(256), 0, stream>>>(P, Q, knn, ps1, pq1);
  k_reduce_stats<<<dim3(128), dim3(256), 0, stream>>>(ps1, pq1, g1, be1, a1, c1);
  k_gemm<2><<<dim3(NEDGE / 128), dim3(256), 0, stream>>>(P, Q, knn, big, W2, b2, a1, c1, ps2, pq2);
  k_reduce_stats<<<dim3(128), dim3(256), 0, stream>>>(ps2, pq2, g2, be2, a2, c2);
  k_gemm<3><<<dim3(NEDGE / 128), dim3(256), 0, stream>>>(P, Q, knn, big, W3, b3, a2, c2, ps3, pq3);
  k_reduce_stats<<<dim3(128), dim3(256), 0, stream>>>(ps3, pq3, g3, be3, a3, c3);
  k_final<<<dim3(N_PTS / 2), dim3(256), 0, stream>>>(big, a3, c3, out);
}